// Round 5
// baseline (1402.614 us; speedup 1.0000x reference)
//
#include <hip/hip_runtime.h>
#include <stdint.h>

// CRITICAL: the reference is XLA-CPU float32; XLA emits separate fmul/fadd
// (no FMA contraction). Disable contraction so our rounding matches.
#pragma clang fp contract(off)

#define NEGF (-1e30f)

// ---------------------------------------------------------------------------
// XLA-CPU float32 math replicas (bit-exact vs reference; verified absmax 0.0).
// ---------------------------------------------------------------------------

__device__ __forceinline__ float xla_exp(float x) {
#pragma clang fp contract(off)
  const float exp_hi = 88.3762626647950f;
  const float exp_lo = -88.3762626647949f;
  const float LOG2EF = 1.44269504088896341f;
  const float C1 = 0.693359375f;
  const float C2 = -2.12194440e-4f;
  float xc = fminf(fmaxf(x, exp_lo), exp_hi);
  float fx = floorf(xc * LOG2EF + 0.5f);
  float tmp = fx * C1;
  float z = fx * C2;
  float xr = xc - tmp;
  xr = xr - z;
  float z2 = xr * xr;
  float y = 1.9875691500E-4f;
  y = y * xr + 1.3981999507E-3f;
  y = y * xr + 8.3334519073E-3f;
  y = y * xr + 4.1665795894E-2f;
  y = y * xr + 1.6666665459E-1f;
  y = y * xr + 5.0000001201E-1f;
  y = y * z2 + xr;
  y = y + 1.0f;
  int n = (int)fx;
  float p2n = __int_as_float((n + 127) << 23);
  float res = y * p2n;
  return fmaxf(res, x);
}

// Specialization for x <= 0: fminf(x, exp_hi) dropped (value-identical there).
__device__ __forceinline__ float xla_exp_np(float x) {
#pragma clang fp contract(off)
  const float exp_lo = -88.3762626647949f;
  const float LOG2EF = 1.44269504088896341f;
  const float C1 = 0.693359375f;
  const float C2 = -2.12194440e-4f;
  float xc = fmaxf(x, exp_lo);
  float fx = floorf(xc * LOG2EF + 0.5f);
  float tmp = fx * C1;
  float z = fx * C2;
  float xr = xc - tmp;
  xr = xr - z;
  float z2 = xr * xr;
  float y = 1.9875691500E-4f;
  y = y * xr + 1.3981999507E-3f;
  y = y * xr + 8.3334519073E-3f;
  y = y * xr + 4.1665795894E-2f;
  y = y * xr + 1.6666665459E-1f;
  y = y * xr + 5.0000001201E-1f;
  y = y * z2 + xr;
  y = y + 1.0f;
  int n = (int)fx;
  float p2n = __int_as_float((n + 127) << 23);
  float res = y * p2n;
  return fmaxf(res, x);
}

__device__ __forceinline__ float xla_log(float xin0) {
#pragma clang fp contract(off)
  float xin = fmaxf(xin0, __int_as_float(0x00800000));
  int bits = __float_as_int(xin);
  int e_int = (bits >> 23) - 126;
  float m = __int_as_float((bits & 0x007fffff) | 0x3f000000);
  float e = (float)e_int;
  const float SQRTHF = 0.707106781186547524f;
  float mlt1 = (m < SQRTHF) ? 1.0f : 0.0f;
  float tmp2 = (m < SQRTHF) ? m : 0.0f;
  float xm = m - 1.0f;
  e = e - mlt1;
  xm = xm + tmp2;
  float z = xm * xm;
  float y = 7.0376836292E-2f;
  y = y * xm + -1.1514610310E-1f;
  y = y * xm + 1.1676998740E-1f;
  y = y * xm + -1.2420140846E-1f;
  y = y * xm + 1.4249322787E-1f;
  y = y * xm + -1.6668057665E-1f;
  y = y * xm + 2.0000714765E-1f;
  y = y * xm + -2.4999993993E-1f;
  y = y * xm + 3.3333331174E-1f;
  y = y * xm;
  y = y * z;
  y = e * -2.12194440e-4f + y;
  y = y - 0.5f * z;
  float out = xm + y;
  out = e * 0.693359375f + out;
  return out;
}

// Specialization for xin >= 1: min-normal clamp dropped (value-identical).
__device__ __forceinline__ float xla_log_ge1(float xin) {
#pragma clang fp contract(off)
  int bits = __float_as_int(xin);
  int e_int = (bits >> 23) - 126;
  float m = __int_as_float((bits & 0x007fffff) | 0x3f000000);
  float e = (float)e_int;
  const float SQRTHF = 0.707106781186547524f;
  float mlt1 = (m < SQRTHF) ? 1.0f : 0.0f;
  float tmp2 = (m < SQRTHF) ? m : 0.0f;
  float xm = m - 1.0f;
  e = e - mlt1;
  xm = xm + tmp2;
  float z = xm * xm;
  float y = 7.0376836292E-2f;
  y = y * xm + -1.1514610310E-1f;
  y = y * xm + 1.1676998740E-1f;
  y = y * xm + -1.2420140846E-1f;
  y = y * xm + 1.4249322787E-1f;
  y = y * xm + -1.6668057665E-1f;
  y = y * xm + 2.0000714765E-1f;
  y = y * xm + -2.4999993993E-1f;
  y = y * xm + 3.3333331174E-1f;
  y = y * xm;
  y = y * z;
  y = e * -2.12194440e-4f + y;
  y = y - 0.5f * z;
  float out = xm + y;
  out = e * 0.693359375f + out;
  return out;
}

__device__ __forceinline__ float xla_log1p(float v) {
#pragma clang fp contract(off)
  float lg = xla_log(v + 1.0f);
  float sm = (-0.5f * v + 1.0f) * v;
  return (fabsf(v) < 1e-4f) ? sm : lg;
}

__device__ __forceinline__ float xla_log1p_unit(float v) {  // v in [0,1]
#pragma clang fp contract(off)
  float lg = xla_log_ge1(v + 1.0f);
  float sm = (-0.5f * v + 1.0f) * v;
  return (fabsf(v) < 1e-4f) ? sm : lg;
}

__device__ __forceinline__ float xla_expm1(float v) {
#pragma clang fp contract(off)
  float ex = xla_exp(v);
  float lgv = ex - 1.0f;
  float sm = v + (v * v) * 0.5f;
  return (fabsf(v) < 1e-5f) ? sm : lgv;
}

__device__ __forceinline__ float xla_logaddexp(float a, float b) {
#pragma clang fp contract(off)
  float amax = fmaxf(a, b);
  float delta = a - b;
  float t = xla_exp(-fabsf(delta));
  return amax + xla_log1p(t);
}

// Cross-lane shift-up-by-1, pure VALU: row_shr:1 within 16-lane rows (lanes
// 0/16/32/48 take old=NEGF); row_bcast15 (0x142) supplies lanes 16/32 from
// lanes 15/31; one cndmask with a loop-invariant mask selects.
__device__ __forceinline__ float shift_up1(float x, bool fix) {
  int xi = __float_as_int(x);
  int negi = __float_as_int(NEGF);
  int a = __builtin_amdgcn_update_dpp(negi, xi, 0x111, 0xf, 0xf, false);
  int b = __builtin_amdgcn_update_dpp(negi, xi, 0x142, 0xf, 0xf, false);
  return __int_as_float(fix ? b : a);
}

// ---------------------------------------------------------------------------
// Single fused kernel. 64 blocks x 512 threads; wave w of block handles row
// r = blockIdx.x*8 + w. 8 waves/block => 2 waves per SIMD co-resident (TLP
// fills dependent-latency stalls). No inter-wave communication at all.
//
// Per step: one SHARED exp evaluation: lanes 1..32 compute the chain's
// t = exp(-|delta|); lanes 0,33..63 compute the PREVIOUS step's decision
// p1 = exp(min(dd,0)) with dd routed in via shfl(lane^32). Lane 0's chain
// output is exactly x2 = lq + carry (proven value-identical to amax+l).
// Decision masks accumulate in a VGPR via uniform-select (cmp+cndmask) and
// are flushed to a global scratch buffer once per 64 steps.
// ---------------------------------------------------------------------------
__global__ __launch_bounds__(512, 2) void dp_kernel(
    const float* __restrict__ scores, const float* __restrict__ unif,
    float* __restrict__ out, uint32_t* __restrict__ maskws) {
#pragma clang fp contract(off)
  const int wid = threadIdx.x >> 6;
  const int lane = threadIdx.x & 63;
  const int r = blockIdx.x * 8 + wid;
  const int b = r >> 2, e = r & 3;

  __shared__ float2 A[8][2][128];     // per-wave double-buffered (theta, lq)
  __shared__ float U[8][2][128];      // per-wave double-buffered u
  __shared__ uint32_t SCR[8][64];     // per-wave walk bounce

  uint32_t* __restrict__ mrow = maskws + (size_t)r * (65 * 64);

  const bool fix = (lane == 16) || (lane == 32);
  const bool is_chain = (lane >= 1 && lane <= 32);
  const bool is_l0 = (lane == 0);

  float carry = is_l0 ? 0.0f : NEGF;
  float pend_dd = 0.0f, pend_u = 2.0f;  // first FIN is a dummy (group 64)
  uint32_t w = 0;

#define PREP(S, TH, LQ)                                                   \
  do {                                                                    \
    float sp_ = xla_logaddexp(-(S), 0.0f);                                \
    (TH) = -sp_ + 1e-7f;                                                  \
    float xm_ = fminf((TH), -1e-7f);                                      \
    float lqa_ = xla_log1p(-xla_exp(xm_));                                \
    float lqb_ = xla_log(-xla_expm1(xm_));                                \
    (LQ) = (xm_ < -0.6931472f) ? lqa_ : lqb_;                             \
  } while (0)

  // chunk C covers steps [CL, CL+127], CL = 4096-128*(C+1); buffer C&1
#define STAGE(C)                                                          \
  do {                                                                    \
    const int CL_ = 4096 - 128 * ((C) + 1);                               \
    const int buf_ = (C) & 1;                                             \
    float s0 = scores[((size_t)b * 4096 + CL_ + lane) * 4 + e];           \
    float s1 = scores[((size_t)b * 4096 + CL_ + 64 + lane) * 4 + e];      \
    float u0 = unif[(size_t)r * 4096 + CL_ + lane];                       \
    float u1 = unif[(size_t)r * 4096 + CL_ + 64 + lane];                  \
    float th0, lq0, th1, lq1;                                             \
    PREP(s0, th0, lq0);                                                   \
    PREP(s1, th1, lq1);                                                   \
    A[wid][buf_][lane] = make_float2(th0, lq0);                           \
    A[wid][buf_][64 + lane] = make_float2(th1, lq1);                      \
    U[wid][buf_][lane] = u0;                                              \
    U[wid][buf_][64 + lane] = u1;                                         \
  } while (0)

  // One DP step for step n (AV={lp,lq}, UV=u_n), fused with FIN for step
  // n+1 (mask slot MS = n+1). m32_/slot are wave-uniform -> cmp+cndmask.
#define STEP(AV, UV, MS)                                                  \
  do {                                                                    \
    float rot_ = __shfl(pend_dd, lane ^ 32);                              \
    float sh_ = shift_up1(carry, fix);                                    \
    float x1_ = (AV).x + sh_;                                             \
    float x2_ = (AV).y + carry;                                           \
    float amax_ = fmaxf(x1_, x2_);                                        \
    float delta_ = x1_ - x2_;                                             \
    float ein_ = is_chain ? -fabsf(delta_) : fminf(rot_, 0.0f);           \
    float E_ = xla_exp_np(ein_);                                          \
    unsigned long long bm_ = __ballot(pend_u < E_);                       \
    uint32_t m32_ = (uint32_t)(bm_ >> 33) | (((uint32_t)bm_ & 1u) << 31); \
    w = (lane == ((MS) & 63)) ? m32_ : w;                                 \
    float l_ = xla_log1p_unit(E_);                                        \
    float nv_ = amax_ + l_;                                               \
    nv_ = is_l0 ? x2_ : nv_;                                              \
    pend_dd = x1_ - nv_;                                                  \
    pend_u = (UV);                                                        \
    carry = nv_;                                                          \
  } while (0)

  STAGE(0);
#pragma unroll 1
  for (int c = 0; c < 32; ++c) {
    const int CL = 4096 - 128 * (c + 1);
    const int buf = c & 1;
    if (c + 1 < 32) STAGE(c + 1);
#pragma unroll 1
    for (int body = 0; body < 16; ++body) {
      const int tb = 127 - body * 8;           // first in-chunk index
      const int Mb = CL + 128 - 8 * body;      // mask slot of first step
      float2 av[8];
      float uv[8];
#pragma unroll
      for (int k = 0; k < 8; ++k) {
        av[k] = A[wid][buf][tb - k];
        uv[k] = U[wid][buf][tb - k];
      }
      STEP(av[0], uv[0], Mb);
      if ((Mb & 63) == 0) mrow[((Mb >> 6) << 6) + lane] = w;  // flush group
#pragma unroll
      for (int k = 1; k < 8; ++k) STEP(av[k], uv[k], Mb - k);
    }
  }
  // final FIN(0) + flush group 0
  {
    float rot_ = __shfl(pend_dd, lane ^ 32);
    float E_ = xla_exp_np(fminf(rot_, 0.0f));
    unsigned long long bm_ = __ballot(pend_u < E_);
    uint32_t m32_ = (uint32_t)(bm_ >> 33) | (((uint32_t)bm_ & 1u) << 31);
    w = (lane == 0) ? m32_ : w;
    mrow[lane] = w;
  }

#undef STEP
#undef STAGE
#undef PREP

  __threadfence();  // drain mask stores to L2 before re-reading

  // ---- budget walk: all lanes lockstep (no divergence), per wave ----
  int rb = 32;
#pragma unroll 1
  for (int g = 0; g < 64; ++g) {
    uint32_t mw = __hip_atomic_load(&mrow[g * 64 + lane], __ATOMIC_RELAXED,
                                    __HIP_MEMORY_SCOPE_AGENT);
    SCR[wid][lane] = mw;
    float myv = 0.0f;
#pragma unroll
    for (int q = 0; q < 64; ++q) {
      uint32_t mm = SCR[wid][q];
      uint32_t bit = (rb > 0) ? ((mm >> ((rb - 1) & 31)) & 1u) : 0u;
      myv = ((lane == q) && bit) ? 1.0f : myv;
      rb -= (int)bit;
    }
    out[((size_t)(b * 64 + g) * 64 + lane) * 4 + e] = myv;
  }
}

// ---------------------------------------------------------------------------
extern "C" void kernel_launch(void* const* d_in, const int* in_sizes, int n_in,
                              void* d_out, int out_size, void* d_ws,
                              size_t ws_size, hipStream_t stream) {
  (void)in_sizes; (void)n_in; (void)out_size; (void)ws_size;
  const float* scores = (const float*)d_in[0];  // (128,64,64,4) f32
  const float* unif = (const float*)d_in[1];    // (512,4096) f32
  float* out = (float*)d_out;                   // (128,64,64,4) f32
  uint32_t* maskws = (uint32_t*)d_ws;           // 512 * 65*64 * 4B = 8.5 MB

  dp_kernel<<<64, 512, 0, stream>>>(scores, unif, out, maskws);
}

// Round 6
// 1220.436 us; speedup vs baseline: 1.1493x; 1.1493x over previous
//
#include <hip/hip_runtime.h>
#include <stdint.h>

// CRITICAL: the reference is XLA-CPU float32; XLA emits separate fmul/fadd
// (no FMA contraction). Disable contraction so our rounding matches.
#pragma clang fp contract(off)

#define NEGF (-1e30f)

// ---------------------------------------------------------------------------
// XLA-CPU float32 math replicas (bit-exact vs reference; verified absmax 0.0).
// ---------------------------------------------------------------------------

__device__ __forceinline__ float xla_exp(float x) {
#pragma clang fp contract(off)
  const float exp_hi = 88.3762626647950f;
  const float exp_lo = -88.3762626647949f;
  const float LOG2EF = 1.44269504088896341f;
  const float C1 = 0.693359375f;
  const float C2 = -2.12194440e-4f;
  float xc = fminf(fmaxf(x, exp_lo), exp_hi);
  float fx = floorf(xc * LOG2EF + 0.5f);
  float tmp = fx * C1;
  float z = fx * C2;
  float xr = xc - tmp;
  xr = xr - z;
  float z2 = xr * xr;
  float y = 1.9875691500E-4f;
  y = y * xr + 1.3981999507E-3f;
  y = y * xr + 8.3334519073E-3f;
  y = y * xr + 4.1665795894E-2f;
  y = y * xr + 1.6666665459E-1f;
  y = y * xr + 5.0000001201E-1f;
  y = y * z2 + xr;
  y = y + 1.0f;
  int n = (int)fx;
  float p2n = __int_as_float((n + 127) << 23);
  float res = y * p2n;
  return fmaxf(res, x);
}

// Specialization for x <= 0: fminf(x, exp_hi) dropped (value-identical there).
__device__ __forceinline__ float xla_exp_np(float x) {
#pragma clang fp contract(off)
  const float exp_lo = -88.3762626647949f;
  const float LOG2EF = 1.44269504088896341f;
  const float C1 = 0.693359375f;
  const float C2 = -2.12194440e-4f;
  float xc = fmaxf(x, exp_lo);
  float fx = floorf(xc * LOG2EF + 0.5f);
  float tmp = fx * C1;
  float z = fx * C2;
  float xr = xc - tmp;
  xr = xr - z;
  float z2 = xr * xr;
  float y = 1.9875691500E-4f;
  y = y * xr + 1.3981999507E-3f;
  y = y * xr + 8.3334519073E-3f;
  y = y * xr + 4.1665795894E-2f;
  y = y * xr + 1.6666665459E-1f;
  y = y * xr + 5.0000001201E-1f;
  y = y * z2 + xr;
  y = y + 1.0f;
  int n = (int)fx;
  float p2n = __int_as_float((n + 127) << 23);
  float res = y * p2n;
  return fmaxf(res, x);
}

__device__ __forceinline__ float xla_log(float xin0) {
#pragma clang fp contract(off)
  float xin = fmaxf(xin0, __int_as_float(0x00800000));
  int bits = __float_as_int(xin);
  int e_int = (bits >> 23) - 126;
  float m = __int_as_float((bits & 0x007fffff) | 0x3f000000);
  float e = (float)e_int;
  const float SQRTHF = 0.707106781186547524f;
  float mlt1 = (m < SQRTHF) ? 1.0f : 0.0f;
  float tmp2 = (m < SQRTHF) ? m : 0.0f;
  float xm = m - 1.0f;
  e = e - mlt1;
  xm = xm + tmp2;
  float z = xm * xm;
  float y = 7.0376836292E-2f;
  y = y * xm + -1.1514610310E-1f;
  y = y * xm + 1.1676998740E-1f;
  y = y * xm + -1.2420140846E-1f;
  y = y * xm + 1.4249322787E-1f;
  y = y * xm + -1.6668057665E-1f;
  y = y * xm + 2.0000714765E-1f;
  y = y * xm + -2.4999993993E-1f;
  y = y * xm + 3.3333331174E-1f;
  y = y * xm;
  y = y * z;
  y = e * -2.12194440e-4f + y;
  y = y - 0.5f * z;
  float out = xm + y;
  out = e * 0.693359375f + out;
  return out;
}

// Specialization for xin >= 1: min-normal clamp dropped (value-identical).
__device__ __forceinline__ float xla_log_ge1(float xin) {
#pragma clang fp contract(off)
  int bits = __float_as_int(xin);
  int e_int = (bits >> 23) - 126;
  float m = __int_as_float((bits & 0x007fffff) | 0x3f000000);
  float e = (float)e_int;
  const float SQRTHF = 0.707106781186547524f;
  float mlt1 = (m < SQRTHF) ? 1.0f : 0.0f;
  float tmp2 = (m < SQRTHF) ? m : 0.0f;
  float xm = m - 1.0f;
  e = e - mlt1;
  xm = xm + tmp2;
  float z = xm * xm;
  float y = 7.0376836292E-2f;
  y = y * xm + -1.1514610310E-1f;
  y = y * xm + 1.1676998740E-1f;
  y = y * xm + -1.2420140846E-1f;
  y = y * xm + 1.4249322787E-1f;
  y = y * xm + -1.6668057665E-1f;
  y = y * xm + 2.0000714765E-1f;
  y = y * xm + -2.4999993993E-1f;
  y = y * xm + 3.3333331174E-1f;
  y = y * xm;
  y = y * z;
  y = e * -2.12194440e-4f + y;
  y = y - 0.5f * z;
  float out = xm + y;
  out = e * 0.693359375f + out;
  return out;
}

__device__ __forceinline__ float xla_log1p(float v) {
#pragma clang fp contract(off)
  float lg = xla_log(v + 1.0f);
  float sm = (-0.5f * v + 1.0f) * v;
  return (fabsf(v) < 1e-4f) ? sm : lg;
}

__device__ __forceinline__ float xla_log1p_unit(float v) {  // v in [0,1]
#pragma clang fp contract(off)
  float lg = xla_log_ge1(v + 1.0f);
  float sm = (-0.5f * v + 1.0f) * v;
  return (fabsf(v) < 1e-4f) ? sm : lg;
}

__device__ __forceinline__ float xla_expm1(float v) {
#pragma clang fp contract(off)
  float ex = xla_exp(v);
  float lgv = ex - 1.0f;
  float sm = v + (v * v) * 0.5f;
  return (fabsf(v) < 1e-5f) ? sm : lgv;
}

__device__ __forceinline__ float xla_logaddexp(float a, float b) {
#pragma clang fp contract(off)
  float amax = fmaxf(a, b);
  float delta = a - b;
  float t = xla_exp(-fabsf(delta));
  return amax + xla_log1p(t);
}

// Cross-lane shift-up-by-1, pure VALU: row_shr:1 within 16-lane rows (lanes
// 0/16/32/48 take old=NEGF); row_bcast15 (0x142) supplies lanes 16/32 from
// lanes 15/31; one cndmask with a loop-invariant mask selects.
__device__ __forceinline__ float shift_up1(float x, bool fix) {
  int xi = __float_as_int(x);
  int negi = __float_as_int(NEGF);
  int a = __builtin_amdgcn_update_dpp(negi, xi, 0x111, 0xf, 0xf, false);
  int b = __builtin_amdgcn_update_dpp(negi, xi, 0x142, 0xf, 0xf, false);
  return __int_as_float(fix ? b : a);
}

__device__ __forceinline__ float rl(float v, int k) {
  return __int_as_float(__builtin_amdgcn_readlane(__float_as_int(v), k));
}

// ---------------------------------------------------------------------------
// One wave per row (512 blocks x 64 threads). PURE-VALU inner loop: inputs
// live in VGPRs (one step per lane), extracted via v_readlane with immediate
// lane index (64-step fully unrolled body). No DS, no SMEM, no exec-divergent
// stores inside the step loop; one global store per 64 steps.
// ---------------------------------------------------------------------------
__global__ __launch_bounds__(64) void dp_kernel(
    const float* __restrict__ scores, const float* __restrict__ unif,
    float* __restrict__ out, uint32_t* __restrict__ maskws) {
#pragma clang fp contract(off)
  const int lane = threadIdx.x;
  const int r = blockIdx.x;
  const int b = r >> 2, e = r & 3;

  __shared__ uint32_t SCR[64];

  uint32_t* __restrict__ mrow = maskws + (size_t)r * 4224;  // 4160 used

  const bool fix = (lane == 16) || (lane == 32);
  const bool elig = (lane >= 1 && lane <= 32);

  float carry = (lane == 0) ? 0.0f : NEGF;
  float pend_dd = 0.0f, pend_u = 2.0f;  // dummy first FIN -> group 64
  uint32_t w = 0;

#define PREP(S, TH, LQ)                                                   \
  do {                                                                    \
    float sp_ = xla_logaddexp(-(S), 0.0f);                                \
    (TH) = -sp_ + 1e-7f;                                                  \
    float xm_ = fminf((TH), -1e-7f);                                      \
    float lqa_ = xla_log1p(-xla_exp(xm_));                                \
    float lqb_ = xla_log(-xla_expm1(xm_));                                \
    (LQ) = (xm_ < -0.6931472f) ? lqa_ : lqb_;                             \
  } while (0)

  // prologue: group t=0 covers n in [4032, 4095]; lane k holds step 4032+k
  float LPc, LQc, Uc;
  {
    float s0 = scores[((size_t)b * 4096 + 4032 + lane) * 4 + e];
    Uc = unif[(size_t)r * 4096 + 4032 + lane];
    PREP(s0, LPc, LQc);
  }

  float LPn = 0.0f, LQn = 0.0f, Un_hold = 0.0f;

#pragma unroll 1
  for (int t = 0; t < 64; ++t) {
    const int bn = 4032 - 64 * t;  // group base step
    float Sn = 0.0f, Un = 0.0f;
    if (t < 63) {
      Sn = scores[((size_t)b * 4096 + (bn - 64) + lane) * 4 + e];
      Un = unif[(size_t)r * 4096 + (bn - 64) + lane];
    }
#pragma unroll
    for (int k = 63; k >= 0; --k) {
      // ---- FIN for step n+1 = bn+k+1 (slot (k+1)&63) ----
      {
        float p1 = xla_exp_np(fminf(pend_dd, 0.0f));
        bool bit = elig && (pend_u < p1);
        unsigned long long bm = __ballot(bit);
        uint32_t m32 = (uint32_t)(bm >> 1);  // budget j at bit j-1
        const int slot = (k + 1) & 63;
        w = (lane == slot) ? m32 : w;
        if (k == 63) mrow[(unsigned)((bn + 64) >> 6) * 64 + lane] = w;
      }
      // mid-group: prep next group's data (off critical path)
      if (k == 32 && t < 63) {
        PREP(Sn, LPn, LQn);
        Un_hold = Un;
      }
      // ---- CHAIN for step n = bn+k ----
      {
        float lp = rl(LPc, k);
        float lq = rl(LQc, k);
        float u = rl(Uc, k);
        float sh = shift_up1(carry, fix);
        float x1 = lp + sh;
        float x2 = lq + carry;
        float amax = fmaxf(x1, x2);
        float delta = x1 - x2;
        float E = xla_exp_np(-fabsf(delta));
        float l = xla_log1p_unit(E);
        float nv = amax + l;
        pend_dd = x1 - nv;
        pend_u = u;
        carry = nv;
      }
    }
    if (t < 63) {
      LPc = LPn;
      LQc = LQn;
      Uc = Un_hold;
    }
  }
  // epilogue: FIN for step 0, flush group 0
  {
    float p1 = xla_exp_np(fminf(pend_dd, 0.0f));
    bool bit = elig && (pend_u < p1);
    unsigned long long bm = __ballot(bit);
    uint32_t m32 = (uint32_t)(bm >> 1);
    w = (lane == 0) ? m32 : w;
    mrow[lane] = w;
  }

#undef PREP

  __threadfence();  // drain mask stores before re-reading

  // ---- budget walk: all lanes lockstep, no divergence ----
  int rb = 32;
#pragma unroll 1
  for (int g = 0; g < 64; ++g) {
    uint32_t mw = __hip_atomic_load(&mrow[g * 64 + lane], __ATOMIC_RELAXED,
                                    __HIP_MEMORY_SCOPE_AGENT);
    SCR[lane] = mw;
    __builtin_amdgcn_s_barrier();
    float myv = 0.0f;
#pragma unroll
    for (int q = 0; q < 64; ++q) {
      uint32_t mm = SCR[q];
      uint32_t bit = (rb > 0) ? ((mm >> ((rb - 1) & 31)) & 1u) : 0u;
      myv = ((lane == q) && bit) ? 1.0f : myv;
      rb -= (int)bit;
    }
    __builtin_amdgcn_s_barrier();
    out[((size_t)(b * 64 + g) * 64 + lane) * 4 + e] = myv;
  }
}

// ---------------------------------------------------------------------------
extern "C" void kernel_launch(void* const* d_in, const int* in_sizes, int n_in,
                              void* d_out, int out_size, void* d_ws,
                              size_t ws_size, hipStream_t stream) {
  (void)in_sizes; (void)n_in; (void)out_size; (void)ws_size;
  const float* scores = (const float*)d_in[0];  // (128,64,64,4) f32
  const float* unif = (const float*)d_in[1];    // (512,4096) f32
  float* out = (float*)d_out;                   // (128,64,64,4) f32
  uint32_t* maskws = (uint32_t*)d_ws;           // 512 * 4224 * 4B = 8.65 MB

  dp_kernel<<<512, 64, 0, stream>>>(scores, unif, out, maskws);
}